// Round 4
// baseline (1547.460 us; speedup 1.0000x reference)
//
#include <hip/hip_runtime.h>
#include <hip/hip_bf16.h>

// ---------- tiny shared helpers ----------

// Detect whether edge_index arrived as int64 (high words all zero) or int32.
// meta[8] = 1 if int32 (stride 1), stays 0 if int64 (stride 2 int32-words).
__global__ void k_detect(const int* __restrict__ ei, int E, int* __restrict__ meta) {
  int i = blockIdx.x * blockDim.x + threadIdx.x;
  if (i < 2048 && i < E && ei[2 * i + 1] != 0) atomicOr(&meta[8], 1);
}

// deg[col] += edge_attr   (self-loop +1 folded into k_dinv)
__global__ void k_deg(const int* __restrict__ ei, const float* __restrict__ ea, int E,
                      const int* __restrict__ meta, float* __restrict__ deg) {
  int e = blockIdx.x * blockDim.x + threadIdx.x;
  if (e >= E) return;
  int st = meta[8] ? 1 : 2;
  atomicAdd(&deg[ei[(size_t)(E + e) * st]], ea[e]);
}

__global__ void k_dinv(float* __restrict__ deg, int N) {
  int i = blockIdx.x * blockDim.x + threadIdx.x;
  if (i < N) deg[i] = 1.0f / sqrtf(deg[i] + 1.0f);  // deg>0 always (self-loop weight 1)
}

// ---------- dense GEMM: C[n][j] = actOut( actIn(A[n][:]) @ W + b ), 256 outputs ----------
template <int KDIM, bool RELU_OUT, bool RELU_IN>
__global__ void __launch_bounds__(256) k_mm(const float* __restrict__ A, int N,
                                            const float* __restrict__ W,
                                            const float* __restrict__ b,
                                            float* __restrict__ C) {
  __shared__ float as[16][KDIM];
  int j = threadIdx.x;
  int base = blockIdx.x * 16;
  int nn = N - base; if (nn > 16) nn = 16; if (nn <= 0) return;
  for (int idx = threadIdx.x; idx < nn * KDIM; idx += 256) {
    int m = idx / KDIM, k = idx - m * KDIM;
    float v = A[(size_t)(base + m) * KDIM + k];
    as[m][k] = RELU_IN ? fmaxf(v, 0.0f) : v;
  }
  __syncthreads();
  float acc[16];
  float bj = (b != nullptr) ? b[j] : 0.0f;
#pragma unroll
  for (int m = 0; m < 16; ++m) acc[m] = bj;
  for (int k = 0; k < KDIM; ++k) {
    float w = W[(size_t)k * 256 + j];
#pragma unroll
    for (int m = 0; m < 16; ++m) acc[m] = fmaf(as[m][k], w, acc[m]);
  }
  for (int m = 0; m < nn; ++m)
    C[(size_t)(base + m) * 256 + j] = RELU_OUT ? fmaxf(acc[m], 0.0f) : acc[m];
}

// out[v] = b + dinv[v]^2 * g[v]       (bias + self-loop message, dense)
__global__ void k_self(int N, const float* __restrict__ dinv, const float* __restrict__ b,
                       const float* __restrict__ g, float* __restrict__ out) {
  int v = blockIdx.x, j = threadIdx.x;
  if (v >= N) return;
  float dv = dinv[v];
  out[(size_t)v * 256 + j] = b[j] + dv * dv * g[(size_t)v * 256 + j];
}

// out[col] += dinv[row]*ea*dinv[col] * g[row]   over ALL E edges (dense)
__global__ void k_edges(const int* __restrict__ ei, const float* __restrict__ ea, int E,
                        const int* __restrict__ meta, const float* __restrict__ dinv,
                        const float* __restrict__ g, float* __restrict__ out) {
  int j = threadIdx.x;
  int st = meta[8] ? 1 : 2;
  for (int e = blockIdx.x; e < E; e += gridDim.x) {
    int u = ei[(size_t)e * st];
    int v = ei[(size_t)(E + e) * st];
    float nrm = dinv[u] * ea[e] * dinv[v];
    atomicAdd(&out[(size_t)v * 256 + j], nrm * g[(size_t)u * 256 + j]);
  }
}

// ---------- head MLP on the target row: ONE block, plain full dot-products ----------
__global__ void __launch_bounds__(512) k_head_all(
    const float* __restrict__ h3, const int* __restrict__ tgt,
    const float* __restrict__ Wo1, const float* __restrict__ bo1,
    const float* __restrict__ Wo2, const float* __restrict__ bo2,
    const float* __restrict__ Wh1, const float* __restrict__ bh1,
    const float* __restrict__ Wh2, const float* __restrict__ bh2,
    const float* __restrict__ Wh3, const float* __restrict__ bh3,
    float* __restrict__ out) {
  __shared__ float sA[512], sB[512];
  int j = threadIdx.x;
  int t = tgt[0];
  if (j < 256) sA[j] = h3[(size_t)t * 256 + j];
  __syncthreads();
  {  // v1 = relu(h3t @ Wo1 + bo1)   [256 -> 512]
    float acc = bo1[j];
    for (int k = 0; k < 256; ++k) acc = fmaf(sA[k], Wo1[(size_t)k * 512 + j], acc);
    sB[j] = fmaxf(acc, 0.0f);
  }
  __syncthreads();
  {  // v2 = v1 @ Wo2 + bo2          [512 -> 512], no relu
    float acc = bo2[j];
    for (int k = 0; k < 512; ++k) acc = fmaf(sB[k], Wo2[(size_t)k * 512 + j], acc);
    sA[j] = acc;
  }
  __syncthreads();
  if (j < 256) {  // v3 = relu(v2 @ Wh1 + bh1)   [512 -> 256]
    float acc = bh1[j];
    for (int k = 0; k < 512; ++k) acc = fmaf(sA[k], Wh1[(size_t)k * 256 + j], acc);
    sB[j] = fmaxf(acc, 0.0f);
  }
  __syncthreads();
  if (j < 128) {  // v4 = relu(v3 @ Wh2 + bh2)   [256 -> 128]
    float acc = bh2[j];
    for (int k = 0; k < 256; ++k) acc = fmaf(sB[k], Wh2[(size_t)k * 128 + j], acc);
    sA[j] = fmaxf(acc, 0.0f);
  }
  __syncthreads();
  if (j < 5) {    // out = v4 @ Wh3 + bh3        [128 -> 5]   (fp32 output!)
    float acc = bh3[j];
    for (int k = 0; k < 128; ++k) acc = fmaf(sA[k], Wh3[(size_t)k * 5 + j], acc);
    out[j] = acc;
  }
}

// Diagnostic: out = [0,0,0,0,D]  (fp32)
__global__ void k_diag(float* __restrict__ out, float D) {
  int tid = threadIdx.x;
  if (tid < 4) out[tid] = 0.0f;
  if (tid == 4) out[tid] = D;
}

extern "C" void kernel_launch(void* const* d_in, const int* in_sizes, int n_in,
                              void* d_out, int out_size, void* d_ws, size_t ws_size,
                              hipStream_t stream) {
  float* out = (float*)d_out;

  // ---- audit the input mapping ----
  static const long long EXP[18] = {5000000, 600000, 300000, 1, 25600, 256, 196608, 768,
                                    131072, 512, 262144, 512, 131072, 256, 32768, 128, 640, 5};
  if (n_in != 18) {
    k_diag<<<1, 64, 0, stream>>>(out, 3.0e6f + 1000.0f * (float)n_in);
    return;
  }
  for (int i = 0; i < 18; ++i) {
    long long s = in_sizes[i];
    bool ok = (s == EXP[i]) || (i == 1 && s == 2 * EXP[1]);  // int64 may count as int32 words
    if (!ok) {
      k_diag<<<1, 64, 0, stream>>>(out, (float)(i + 1) * 1.0e5f);
      return;
    }
  }

  const float* x   = (const float*)d_in[0];
  const int*   ei  = (const int*)d_in[1];
  const float* ea  = (const float*)d_in[2];
  const int*   tgt = (const int*)d_in[3];
  const float* Wi  = (const float*)d_in[4];
  const float* bi  = (const float*)d_in[5];
  const float* Wg  = (const float*)d_in[6];
  const float* bg  = (const float*)d_in[7];
  const float* Wo1 = (const float*)d_in[8];
  const float* bo1 = (const float*)d_in[9];
  const float* Wo2 = (const float*)d_in[10];
  const float* bo2 = (const float*)d_in[11];
  const float* Wh1 = (const float*)d_in[12];
  const float* bh1 = (const float*)d_in[13];
  const float* Wh2 = (const float*)d_in[14];
  const float* bh2 = (const float*)d_in[15];
  const float* Wh3 = (const float*)d_in[16];
  const float* bh3 = (const float*)d_in[17];

  const int N = 50000, E = 300000;

  // ---- workspace: deg | meta | A[N,256] | B[N,256] ----
  auto al = [](size_t b) { return (b + 255) & ~(size_t)255; };
  size_t need = al((size_t)N * 4) + al(256) + 2 * al((size_t)N * 256 * 4);
  if (need > ws_size) {
    k_diag<<<1, 64, 0, stream>>>(out, 9.0e6f + (float)(ws_size >> 20));
    return;
  }
  char* ws = (char*)d_ws;
  size_t off = 0;
  auto alloc = [&](size_t bytes) { char* p = ws + off; off += al(bytes); return p; };
  float* deg  = (float*)alloc((size_t)N * 4);
  int*   meta = (int*)alloc(256);
  float* A    = (float*)alloc((size_t)N * 256 * 4);
  float* B    = (float*)alloc((size_t)N * 256 * 4);

  hipMemsetAsync(deg, 0, (size_t)N * 4, stream);
  hipMemsetAsync(meta, 0, 256, stream);

  dim3 b256(256);
  int gE = (E + 255) / 256;
  int gN = (N + 255) / 256;
  int gMM = (N + 15) / 16;

  k_detect<<<8, b256, 0, stream>>>(ei, E, meta);
  k_deg<<<gE, b256, 0, stream>>>(ei, ea, E, meta, deg);
  k_dinv<<<gN, b256, 0, stream>>>(deg, N);

  // h0 = relu(x @ Wi + bi)   -> A
  k_mm<100, true, false><<<gMM, b256, 0, stream>>>(x, N, Wi, bi, A);

  // 3 GCN layers, dense: B = actIn(A) @ Wk ; A = bk + dinv^2*B ; A[col] += norm*B[row]
  for (int k = 0; k < 3; ++k) {
    const float* Wk = Wg + (size_t)k * 256 * 256;
    const float* bk = bg + (size_t)k * 256;
    if (k == 0)
      k_mm<256, false, false><<<gMM, b256, 0, stream>>>(A, N, Wk, nullptr, B);
    else
      k_mm<256, false, true ><<<gMM, b256, 0, stream>>>(A, N, Wk, nullptr, B);
    k_self<<<N, b256, 0, stream>>>(N, deg, bk, B, A);
    k_edges<<<8192, b256, 0, stream>>>(ei, ea, E, meta, deg, B, A);
  }

  // head MLP on target row of A (= h3), fp32 output
  k_head_all<<<1, 512, 0, stream>>>(A, tgt, Wo1, bo1, Wo2, bo2,
                                    Wh1, bh1, Wh2, bh2, Wh3, bh3, out);
}

// Round 5
// 137.815 us; speedup vs baseline: 11.2286x; 11.2286x over previous
//
#include <hip/hip_runtime.h>

#define HDIM 256
#define CAPN 4096
#define CAPE (CAPN * 8)

// Slot-map convention: 0 = absent, 1 = transient claim, s+2 = compact slot s.

// Detect whether edge_index arrived as int64 (high words all zero) or int32.
// meta[8] = 1 if int32 (stride 1), stays 0 if int64 (stride 2 int32-words).
__global__ void k_detect(const int* __restrict__ ei, int E, int* __restrict__ meta) {
  int i = blockIdx.x * blockDim.x + threadIdx.x;
  if (i < 2048 && i < E && ei[2 * i + 1] != 0) atomicOr(&meta[8], 1);
}

// deg[col] += edge_attr   (self-loop +1 folded into k_dinv_seed)
__global__ void k_deg(const int* __restrict__ ei, const float* __restrict__ ea, int E,
                      const int* __restrict__ meta, float* __restrict__ deg) {
  int e = blockIdx.x * blockDim.x + threadIdx.x;
  if (e >= E) return;
  int st = meta[8] ? 1 : 2;
  atomicAdd(&deg[ei[(size_t)(E + e) * st]], ea[e]);
}

// dinv = rsqrt(deg + 1) in place; global thread 0 seeds level-3 set = {target}
__global__ void k_dinv_seed(float* __restrict__ deg, int N, const int* __restrict__ tgt,
                            int* __restrict__ slot3, int* __restrict__ list3,
                            int* __restrict__ meta) {
  int i = blockIdx.x * blockDim.x + threadIdx.x;
  if (i < N) deg[i] = 1.0f / sqrtf(deg[i] + 1.0f);
  if (i == 0) { int t = tgt[0]; slot3[t] = 2; list3[0] = t; meta[3] = 1; }
}

// One frontier step: S_{l-1} = in-neighbors(S_l) ∪ S_l, plus the layer's edge list.
// Seeds (union part) and edge appends both CAS-claim, so they can share a kernel.
__global__ void k_expand(const int* __restrict__ ei, int E, int* __restrict__ meta,
                         const int* __restrict__ slot_hi, const int* __restrict__ list_hi,
                         int cnt_hi_idx, int* __restrict__ slot_lo, int* __restrict__ list_lo,
                         int cnt_lo_idx, int* __restrict__ elist, int ecnt_idx) {
  int tid = blockIdx.x * blockDim.x + threadIdx.x;
  int total = gridDim.x * blockDim.x;
  int st = meta[8] ? 1 : 2;
  int nhi = meta[cnt_hi_idx]; if (nhi > CAPN) nhi = CAPN;
  if (tid < nhi) {                      // self-loop union: S_l ⊆ S_{l-1}
    int v = list_hi[tid];
    if (atomicCAS(&slot_lo[v], 0, 1) == 0) {
      int s = atomicAdd(&meta[cnt_lo_idx], 1);
      if (s < CAPN) { list_lo[s] = v; slot_lo[v] = s + 2; }
    }
  }
  for (int e = tid; e < E; e += total) {
    int c = ei[(size_t)(E + e) * st];
    if (slot_hi[c] >= 2) {
      int r = ei[(size_t)e * st];
      int s = atomicAdd(&meta[ecnt_idx], 1);
      if (s < CAPE) elist[s] = e;
      if (atomicCAS(&slot_lo[r], 0, 1) == 0) {
        int s2 = atomicAdd(&meta[cnt_lo_idx], 1);
        if (s2 < CAPN) { list_lo[s2] = r; slot_lo[r] = s2 + 2; }
      }
    }
  }
}

// h0[slot] = relu(x[u] @ Wi + bi) for S0 nodes
__global__ void k_h0(const int* __restrict__ meta, const int* __restrict__ list0,
                     const float* __restrict__ x, const float* __restrict__ Wi,
                     const float* __restrict__ bi, float* __restrict__ h) {
  __shared__ float xs[128];
  int n0 = meta[0]; if (n0 > CAPN) n0 = CAPN;
  int j = threadIdx.x;
  for (int s = blockIdx.x; s < n0; s += gridDim.x) {
    int u = list0[s];
    if (j < 100) xs[j] = x[(size_t)u * 100 + j];
    __syncthreads();
    float acc = bi[j];
#pragma unroll 4
    for (int k = 0; k < 100; ++k) acc = fmaf(xs[k], Wi[k * HDIM + j], acc);
    h[(size_t)s * HDIM + j] = fmaxf(acc, 0.0f);
    __syncthreads();
  }
}

// g[slot] = (relu?)(hin[slot]) @ W  over level-`lvl` rows
template <bool RELU_IN>
__global__ void k_gemv(const int* __restrict__ meta, int lvl, const float* __restrict__ hin,
                       const float* __restrict__ W, float* __restrict__ g) {
  __shared__ float hs[HDIM];
  int n = meta[lvl]; if (n > CAPN) n = CAPN;
  int j = threadIdx.x;
  for (int s = blockIdx.x; s < n; s += gridDim.x) {
    float hv = hin[(size_t)s * HDIM + j];
    hs[j] = RELU_IN ? fmaxf(hv, 0.0f) : hv;
    __syncthreads();
    float acc = 0.0f;
#pragma unroll 8
    for (int m = 0; m < HDIM; ++m) acc = fmaf(hs[m], W[m * HDIM + j], acc);
    g[(size_t)s * HDIM + j] = acc;
    __syncthreads();
  }
}

// hout[slot_out(v)] = b + dinv(v)^2 * g[slot_in(v)]   (bias + self-loop message)
__global__ void k_init_self(const int* __restrict__ meta, int lvl_out,
                            const int* __restrict__ list_out, const int* __restrict__ slot_in,
                            const float* __restrict__ dinv, const float* __restrict__ bgl,
                            const float* __restrict__ g, float* __restrict__ hout) {
  int n = meta[lvl_out]; if (n > CAPN) n = CAPN;
  int j = threadIdx.x;
  for (int s = blockIdx.x; s < n; s += gridDim.x) {
    int v = list_out[s];
    int si = slot_in[v];
    float dv = dinv[v];
    float gv = (si >= 2) ? g[(size_t)(si - 2) * HDIM + j] : 0.0f;
    hout[(size_t)s * HDIM + j] = bgl[j] + dv * dv * gv;
  }
}

// hout[slot_out(col)] += dinv(row)*ea*dinv(col) * g[slot_in(row)] over active edges
__global__ void k_scatter(const int* __restrict__ ei, int E, const int* __restrict__ meta,
                          int ecnt_idx, const int* __restrict__ elist,
                          const float* __restrict__ ea, const float* __restrict__ dinv,
                          const int* __restrict__ slot_in, const int* __restrict__ slot_out,
                          const float* __restrict__ g, float* __restrict__ hout) {
  int ne = meta[ecnt_idx]; if (ne > CAPE) ne = CAPE;
  int st = meta[8] ? 1 : 2;
  int j = threadIdx.x;
  for (int i = blockIdx.x; i < ne; i += gridDim.x) {
    int e = elist[i];
    int u = ei[(size_t)e * st];
    int v = ei[(size_t)(E + e) * st];
    int su = slot_in[u], sv = slot_out[v];
    if (su < 2 || sv < 2) continue;
    float nrm = dinv[u] * ea[e] * dinv[v];
    atomicAdd(&hout[(size_t)(sv - 2) * HDIM + j], nrm * g[(size_t)(su - 2) * HDIM + j]);
  }
}

// Head MLP on compact row 0 (= target node). Proven in round 4, fp32 output.
// Side-channel: if any frontier count overflowed its cap, out[4] = code*1e6.
__global__ void __launch_bounds__(512) k_head_all(
    const float* __restrict__ h3row, const int* __restrict__ meta,
    const float* __restrict__ Wo1, const float* __restrict__ bo1,
    const float* __restrict__ Wo2, const float* __restrict__ bo2,
    const float* __restrict__ Wh1, const float* __restrict__ bh1,
    const float* __restrict__ Wh2, const float* __restrict__ bh2,
    const float* __restrict__ Wh3, const float* __restrict__ bh3,
    float* __restrict__ out) {
  __shared__ float sA[512], sB[512];
  int j = threadIdx.x;
  if (j < 256) sA[j] = h3row[j];
  __syncthreads();
  {  // v1 = relu(h3t @ Wo1 + bo1)   [256 -> 512]
    float acc = bo1[j];
    for (int k = 0; k < 256; ++k) acc = fmaf(sA[k], Wo1[(size_t)k * 512 + j], acc);
    sB[j] = fmaxf(acc, 0.0f);
  }
  __syncthreads();
  {  // v2 = v1 @ Wo2 + bo2          [512 -> 512], no relu
    float acc = bo2[j];
    for (int k = 0; k < 512; ++k) acc = fmaf(sB[k], Wo2[(size_t)k * 512 + j], acc);
    sA[j] = acc;
  }
  __syncthreads();
  if (j < 256) {  // v3 = relu(v2 @ Wh1 + bh1)   [512 -> 256]
    float acc = bh1[j];
    for (int k = 0; k < 512; ++k) acc = fmaf(sA[k], Wh1[(size_t)k * 256 + j], acc);
    sB[j] = fmaxf(acc, 0.0f);
  }
  __syncthreads();
  if (j < 128) {  // v4 = relu(v3 @ Wh2 + bh2)   [256 -> 128]
    float acc = bh2[j];
    for (int k = 0; k < 256; ++k) acc = fmaf(sB[k], Wh2[(size_t)k * 128 + j], acc);
    sA[j] = fmaxf(acc, 0.0f);
  }
  __syncthreads();
  if (j < 5) {    // out = v4 @ Wh3 + bh3        [128 -> 5]
    float acc = bh3[j];
    for (int k = 0; k < 128; ++k) acc = fmaf(sA[k], Wh3[(size_t)k * 5 + j], acc);
    if (j == 4) {
      int B = 0;
      if (meta[0] > CAPN || meta[1] > CAPN || meta[2] > CAPN) B |= 1;
      if (meta[4] > CAPE || meta[5] > CAPE || meta[6] > CAPE) B |= 2;
      if (B) acc = 1.0e6f * (float)B;
    }
    out[j] = acc;
  }
}

// Diagnostic: out = [0,0,0,0,D]  (fp32)
__global__ void k_diag(float* __restrict__ out, float D) {
  int tid = threadIdx.x;
  if (tid < 4) out[tid] = 0.0f;
  if (tid == 4) out[tid] = D;
}

extern "C" void kernel_launch(void* const* d_in, const int* in_sizes, int n_in,
                              void* d_out, int out_size, void* d_ws, size_t ws_size,
                              hipStream_t stream) {
  float* out = (float*)d_out;

  // ---- audit the input mapping (proven good in round 4; keep as tripwire) ----
  static const long long EXP[18] = {5000000, 600000, 300000, 1, 25600, 256, 196608, 768,
                                    131072, 512, 262144, 512, 131072, 256, 32768, 128, 640, 5};
  if (n_in != 18) {
    k_diag<<<1, 64, 0, stream>>>(out, 3.0e6f + 1000.0f * (float)n_in);
    return;
  }
  for (int i = 0; i < 18; ++i) {
    long long s = in_sizes[i];
    bool ok = (s == EXP[i]) || (i == 1 && s == 2 * EXP[1]);  // int64 may count as int32 words
    if (!ok) {
      k_diag<<<1, 64, 0, stream>>>(out, (float)(i + 1) * 1.0e5f);
      return;
    }
  }

  const float* x   = (const float*)d_in[0];
  const int*   ei  = (const int*)d_in[1];
  const float* ea  = (const float*)d_in[2];
  const int*   tgt = (const int*)d_in[3];
  const float* Wi  = (const float*)d_in[4];
  const float* bi  = (const float*)d_in[5];
  const float* Wg  = (const float*)d_in[6];
  const float* bg  = (const float*)d_in[7];
  const float* Wo1 = (const float*)d_in[8];
  const float* bo1 = (const float*)d_in[9];
  const float* Wo2 = (const float*)d_in[10];
  const float* bo2 = (const float*)d_in[11];
  const float* Wh1 = (const float*)d_in[12];
  const float* bh1 = (const float*)d_in[13];
  const float* Wh2 = (const float*)d_in[14];
  const float* bh2 = (const float*)d_in[15];
  const float* Wh3 = (const float*)d_in[16];
  const float* bh3 = (const float*)d_in[17];

  const int N = 50000, E = 300000;

  // ---- workspace: [zero span: deg | meta | slot0..3] | lists | elists | g,hA,hB ----
  auto al = [](size_t b) { return (b + 255) & ~(size_t)255; };
  char* ws = (char*)d_ws;
  size_t off = 0;
  auto alloc = [&](size_t bytes) { char* p = ws + off; off += al(bytes); return p; };

  float* deg  = (float*)alloc((size_t)N * 4);
  int*   meta = (int*)alloc(256);
  int* slot[4];
  for (int l = 0; l < 4; ++l) slot[l] = (int*)alloc((size_t)N * 4);
  size_t zero_bytes = off;                  // everything above starts at 0 each call
  int* list[4];
  for (int l = 0; l < 4; ++l) list[l] = (int*)alloc((size_t)CAPN * 4);
  int* elist[3];
  for (int k = 0; k < 3; ++k) elist[k] = (int*)alloc((size_t)CAPE * 4);
  float* g  = (float*)alloc((size_t)CAPN * HDIM * 4);
  float* hA = (float*)alloc((size_t)CAPN * HDIM * 4);
  float* hB = (float*)alloc((size_t)CAPN * HDIM * 4);

  if (off > ws_size) {
    k_diag<<<1, 64, 0, stream>>>(out, 9.0e6f + (float)(ws_size >> 20));
    return;
  }

  hipMemsetAsync(ws, 0, zero_bytes, stream);  // deg=0, meta=0, slot maps=absent

  dim3 b256(256);
  int gE = (E + 255) / 256;
  int gN = (N + 255) / 256;

  k_detect<<<8, b256, 0, stream>>>(ei, E, meta);
  k_deg<<<gE, b256, 0, stream>>>(ei, ea, E, meta, deg);
  k_dinv_seed<<<gN, b256, 0, stream>>>(deg, N, tgt, slot[3], list[3], meta);

  // frontier: S3 -> S2 -> S1 -> S0, collecting per-layer edge lists
  for (int l = 3; l >= 1; --l)
    k_expand<<<gE, b256, 0, stream>>>(ei, E, meta, slot[l], list[l], l,
                                      slot[l - 1], list[l - 1], l - 1,
                                      elist[l - 1], 4 + (l - 1));

  // input projection for S0
  k_h0<<<256, b256, 0, stream>>>(meta, list[0], x, Wi, bi, hA);

  // 3 GCN layers on the active subgraph
  float* hin = hA;
  float* hout = hB;
  for (int k = 0; k < 3; ++k) {
    const float* Wk = Wg + (size_t)k * HDIM * HDIM;
    const float* bk = bg + (size_t)k * HDIM;
    if (k == 0)
      k_gemv<false><<<256, b256, 0, stream>>>(meta, k, hin, Wk, g);
    else
      k_gemv<true><<<256, b256, 0, stream>>>(meta, k, hin, Wk, g);
    k_init_self<<<128, b256, 0, stream>>>(meta, k + 1, list[k + 1], slot[k], deg, bk, g, hout);
    k_scatter<<<256, b256, 0, stream>>>(ei, E, meta, 4 + k, elist[k], ea, deg,
                                        slot[k], slot[k + 1], g, hout);
    float* tmp = hin; hin = hout; hout = tmp;
  }
  // hin row 0 = target node's h3 (slot 0 of level 3 by construction)

  k_head_all<<<1, 512, 0, stream>>>(hin, meta, Wo1, bo1, Wo2, bo2,
                                    Wh1, bh1, Wh2, bh2, Wh3, bh3, out);
}

// Round 6
// 103.011 us; speedup vs baseline: 15.0222x; 1.3379x over previous
//
#include <hip/hip_runtime.h>

#define HDIM 256
#define CAPN 4096
#define CAPE (CAPN * 8)

// Slot-map convention: 0 = absent, 1 = transient claim, s+2 = compact slot s.

// Detect whether edge_index arrived as int64 (high words all zero) or int32.
// meta[8] = 1 if int32 (stride 1), stays 0 if int64 (stride 2 int32-words).
__global__ void k_detect(const int* __restrict__ ei, int E, int* __restrict__ meta) {
  int i = blockIdx.x * blockDim.x + threadIdx.x;
  if (i < 2048 && i < E && ei[2 * i + 1] != 0) atomicOr(&meta[8], 1);
}

// deg[col] += edge_attr   (self-loop +1 folded into k_dinv_seed)
__global__ void k_deg(const int* __restrict__ ei, const float* __restrict__ ea, int E,
                      const int* __restrict__ meta, float* __restrict__ deg) {
  int e = blockIdx.x * blockDim.x + threadIdx.x;
  if (e >= E) return;
  int st = meta[8] ? 1 : 2;
  atomicAdd(&deg[ei[(size_t)(E + e) * st]], ea[e]);
}

// dinv = rsqrt(deg + 1) in place; global thread 0 seeds level-3 set = {target}
__global__ void k_dinv_seed(float* __restrict__ deg, int N, const int* __restrict__ tgt,
                            int* __restrict__ slot3, int* __restrict__ list3,
                            int* __restrict__ meta) {
  int i = blockIdx.x * blockDim.x + threadIdx.x;
  if (i < N) deg[i] = 1.0f / sqrtf(deg[i] + 1.0f);
  if (i == 0) { int t = tgt[0]; slot3[t] = 2; list3[0] = t; meta[3] = 1; }
}

// One frontier step: S_{l-1} = in-neighbors(S_l) ∪ S_l, plus the layer's edge list.
__global__ void k_expand(const int* __restrict__ ei, int E, int* __restrict__ meta,
                         const int* __restrict__ slot_hi, const int* __restrict__ list_hi,
                         int cnt_hi_idx, int* __restrict__ slot_lo, int* __restrict__ list_lo,
                         int cnt_lo_idx, int* __restrict__ elist, int ecnt_idx) {
  int tid = blockIdx.x * blockDim.x + threadIdx.x;
  int total = gridDim.x * blockDim.x;
  int st = meta[8] ? 1 : 2;
  int nhi = meta[cnt_hi_idx]; if (nhi > CAPN) nhi = CAPN;
  if (tid < nhi) {                      // self-loop union: S_l ⊆ S_{l-1}
    int v = list_hi[tid];
    if (atomicCAS(&slot_lo[v], 0, 1) == 0) {
      int s = atomicAdd(&meta[cnt_lo_idx], 1);
      if (s < CAPN) { list_lo[s] = v; slot_lo[v] = s + 2; }
    }
  }
  for (int e = tid; e < E; e += total) {
    int c = ei[(size_t)(E + e) * st];
    if (slot_hi[c] >= 2) {
      int r = ei[(size_t)e * st];
      int s = atomicAdd(&meta[ecnt_idx], 1);
      if (s < CAPE) elist[s] = e;
      if (atomicCAS(&slot_lo[r], 0, 1) == 0) {
        int s2 = atomicAdd(&meta[cnt_lo_idx], 1);
        if (s2 < CAPN) { list_lo[s2] = r; slot_lo[r] = s2 + 2; }
      }
    }
  }
}

// h0[slot] = relu(x[u] @ Wi + bi) for S0 nodes
__global__ void k_h0(const int* __restrict__ meta, const int* __restrict__ list0,
                     const float* __restrict__ x, const float* __restrict__ Wi,
                     const float* __restrict__ bi, float* __restrict__ h) {
  __shared__ float xs[128];
  int n0 = meta[0]; if (n0 > CAPN) n0 = CAPN;
  int j = threadIdx.x;
  for (int s = blockIdx.x; s < n0; s += gridDim.x) {
    int u = list0[s];
    if (j < 100) xs[j] = x[(size_t)u * 100 + j];
    __syncthreads();
    float acc = bi[j];
#pragma unroll 4
    for (int k = 0; k < 100; ++k) acc = fmaf(xs[k], Wi[k * HDIM + j], acc);
    h[(size_t)s * HDIM + j] = fmaxf(acc, 0.0f);
    __syncthreads();
  }
}

// g[slot] = (relu?)(hin[slot]) @ W  over level-`lvl` rows
template <bool RELU_IN>
__global__ void k_gemv(const int* __restrict__ meta, int lvl, const float* __restrict__ hin,
                       const float* __restrict__ W, float* __restrict__ g) {
  __shared__ float hs[HDIM];
  int n = meta[lvl]; if (n > CAPN) n = CAPN;
  int j = threadIdx.x;
  for (int s = blockIdx.x; s < n; s += gridDim.x) {
    float hv = hin[(size_t)s * HDIM + j];
    hs[j] = RELU_IN ? fmaxf(hv, 0.0f) : hv;
    __syncthreads();
    float acc = 0.0f;
#pragma unroll 8
    for (int m = 0; m < HDIM; ++m) acc = fmaf(hs[m], W[m * HDIM + j], acc);
    g[(size_t)s * HDIM + j] = acc;
    __syncthreads();
  }
}

// hout[slot_out(v)] = b + dinv(v)^2 * g[slot_in(v)]   (bias + self-loop message)
__global__ void k_init_self(const int* __restrict__ meta, int lvl_out,
                            const int* __restrict__ list_out, const int* __restrict__ slot_in,
                            const float* __restrict__ dinv, const float* __restrict__ bgl,
                            const float* __restrict__ g, float* __restrict__ hout) {
  int n = meta[lvl_out]; if (n > CAPN) n = CAPN;
  int j = threadIdx.x;
  for (int s = blockIdx.x; s < n; s += gridDim.x) {
    int v = list_out[s];
    int si = slot_in[v];
    float dv = dinv[v];
    float gv = (si >= 2) ? g[(size_t)(si - 2) * HDIM + j] : 0.0f;
    hout[(size_t)s * HDIM + j] = bgl[j] + dv * dv * gv;
  }
}

// hout[slot_out(col)] += dinv(row)*ea*dinv(col) * g[slot_in(row)] over active edges
__global__ void k_scatter(const int* __restrict__ ei, int E, const int* __restrict__ meta,
                          int ecnt_idx, const int* __restrict__ elist,
                          const float* __restrict__ ea, const float* __restrict__ dinv,
                          const int* __restrict__ slot_in, const int* __restrict__ slot_out,
                          const float* __restrict__ g, float* __restrict__ hout) {
  int ne = meta[ecnt_idx]; if (ne > CAPE) ne = CAPE;
  int st = meta[8] ? 1 : 2;
  int j = threadIdx.x;
  for (int i = blockIdx.x; i < ne; i += gridDim.x) {
    int e = elist[i];
    int u = ei[(size_t)e * st];
    int v = ei[(size_t)(E + e) * st];
    int su = slot_in[u], sv = slot_out[v];
    if (su < 2 || sv < 2) continue;
    float nrm = dinv[u] * ea[e] * dinv[v];
    atomicAdd(&hout[(size_t)(sv - 2) * HDIM + j], nrm * g[(size_t)(su - 2) * HDIM + j]);
  }
}

// Head MLP stage (proven in rounds 1-2): vout[j] = act(vin @ W + b),
// 64 outputs x 4 K-chunks per 256-thread block, KOUT/64 blocks.
template <int KIN, int KOUT, bool RELU>
__global__ void __launch_bounds__(256) k_head(const float* __restrict__ vin,
                                              const float* __restrict__ W,
                                              const float* __restrict__ b,
                                              float* __restrict__ vout) {
  __shared__ float vs[KIN];
  __shared__ float red[4][64];
  int tx = threadIdx.x & 63, ty = threadIdx.x >> 6;
  for (int k = threadIdx.x; k < KIN; k += 256) vs[k] = vin[k];
  __syncthreads();
  int j = blockIdx.x * 64 + tx;
  const int KQ = KIN / 4;
  float acc = 0.0f;
#pragma unroll 4
  for (int k = ty * KQ; k < (ty + 1) * KQ; ++k) acc = fmaf(vs[k], W[(size_t)k * KOUT + j], acc);
  red[ty][tx] = acc;
  __syncthreads();
  if (ty == 0) {
    float r = red[0][tx] + red[1][tx] + red[2][tx] + red[3][tx] + b[j];
    vout[j] = RELU ? fmaxf(r, 0.0f) : r;
  }
}

// Final [128] @ [128,5] + b -> 5 fp32 outputs, with overflow side-channel on out[4].
__global__ void k_final(const float* __restrict__ vin, const float* __restrict__ W,
                        const float* __restrict__ b, const int* __restrict__ meta,
                        float* __restrict__ out) {
  __shared__ float vs[128];
  int tid = threadIdx.x;
  vs[tid] = vin[tid];
  __syncthreads();
  if (tid < 5) {
    float acc = b[tid];
#pragma unroll 4
    for (int k = 0; k < 128; ++k) acc = fmaf(vs[k], W[k * 5 + tid], acc);
    if (tid == 4) {
      int B = 0;
      if (meta[0] > CAPN || meta[1] > CAPN || meta[2] > CAPN) B |= 1;
      if (meta[4] > CAPE || meta[5] > CAPE || meta[6] > CAPE) B |= 2;
      if (B) acc = 1.0e6f * (float)B;
    }
    out[tid] = acc;
  }
}

// Diagnostic: out = [0,0,0,0,D]  (fp32)
__global__ void k_diag(float* __restrict__ out, float D) {
  int tid = threadIdx.x;
  if (tid < 4) out[tid] = 0.0f;
  if (tid == 4) out[tid] = D;
}

extern "C" void kernel_launch(void* const* d_in, const int* in_sizes, int n_in,
                              void* d_out, int out_size, void* d_ws, size_t ws_size,
                              hipStream_t stream) {
  float* out = (float*)d_out;

  // ---- audit the input mapping (proven good; keep as tripwire) ----
  static const long long EXP[18] = {5000000, 600000, 300000, 1, 25600, 256, 196608, 768,
                                    131072, 512, 262144, 512, 131072, 256, 32768, 128, 640, 5};
  if (n_in != 18) {
    k_diag<<<1, 64, 0, stream>>>(out, 3.0e6f + 1000.0f * (float)n_in);
    return;
  }
  for (int i = 0; i < 18; ++i) {
    long long s = in_sizes[i];
    bool ok = (s == EXP[i]) || (i == 1 && s == 2 * EXP[1]);  // int64 may count as int32 words
    if (!ok) {
      k_diag<<<1, 64, 0, stream>>>(out, (float)(i + 1) * 1.0e5f);
      return;
    }
  }

  const float* x   = (const float*)d_in[0];
  const int*   ei  = (const int*)d_in[1];
  const float* ea  = (const float*)d_in[2];
  const int*   tgt = (const int*)d_in[3];
  const float* Wi  = (const float*)d_in[4];
  const float* bi  = (const float*)d_in[5];
  const float* Wg  = (const float*)d_in[6];
  const float* bg  = (const float*)d_in[7];
  const float* Wo1 = (const float*)d_in[8];
  const float* bo1 = (const float*)d_in[9];
  const float* Wo2 = (const float*)d_in[10];
  const float* bo2 = (const float*)d_in[11];
  const float* Wh1 = (const float*)d_in[12];
  const float* bh1 = (const float*)d_in[13];
  const float* Wh2 = (const float*)d_in[14];
  const float* bh2 = (const float*)d_in[15];
  const float* Wh3 = (const float*)d_in[16];
  const float* bh3 = (const float*)d_in[17];

  const int N = 50000, E = 300000;

  // ---- workspace: [zero span: deg | meta | slot0..3] | lists | elists | g,hA,hB | headv ----
  auto al = [](size_t b) { return (b + 255) & ~(size_t)255; };
  char* ws = (char*)d_ws;
  size_t off = 0;
  auto alloc = [&](size_t bytes) { char* p = ws + off; off += al(bytes); return p; };

  float* deg  = (float*)alloc((size_t)N * 4);
  int*   meta = (int*)alloc(256);
  int* slot[4];
  for (int l = 0; l < 4; ++l) slot[l] = (int*)alloc((size_t)N * 4);
  size_t zero_bytes = off;                  // everything above starts at 0 each call
  int* list[4];
  for (int l = 0; l < 4; ++l) list[l] = (int*)alloc((size_t)CAPN * 4);
  int* elist[3];
  for (int k = 0; k < 3; ++k) elist[k] = (int*)alloc((size_t)CAPE * 4);
  float* g  = (float*)alloc((size_t)CAPN * HDIM * 4);
  float* hA = (float*)alloc((size_t)CAPN * HDIM * 4);
  float* hB = (float*)alloc((size_t)CAPN * HDIM * 4);
  float* headv = (float*)alloc(4096);
  float* v1 = headv;
  float* v2 = headv + 512;

  if (off > ws_size) {
    k_diag<<<1, 64, 0, stream>>>(out, 9.0e6f + (float)(ws_size >> 20));
    return;
  }

  hipMemsetAsync(ws, 0, zero_bytes, stream);  // deg=0, meta=0, slot maps=absent

  dim3 b256(256);
  int gE = (E + 255) / 256;
  int gN = (N + 255) / 256;

  k_detect<<<8, b256, 0, stream>>>(ei, E, meta);
  k_deg<<<gE, b256, 0, stream>>>(ei, ea, E, meta, deg);
  k_dinv_seed<<<gN, b256, 0, stream>>>(deg, N, tgt, slot[3], list[3], meta);

  // frontier: S3 -> S2 -> S1 -> S0, collecting per-layer edge lists
  for (int l = 3; l >= 1; --l)
    k_expand<<<gE, b256, 0, stream>>>(ei, E, meta, slot[l], list[l], l,
                                      slot[l - 1], list[l - 1], l - 1,
                                      elist[l - 1], 4 + (l - 1));

  // input projection for S0
  k_h0<<<256, b256, 0, stream>>>(meta, list[0], x, Wi, bi, hA);

  // 3 GCN layers on the active subgraph
  float* hin = hA;
  float* hout = hB;
  for (int k = 0; k < 3; ++k) {
    const float* Wk = Wg + (size_t)k * HDIM * HDIM;
    const float* bk = bg + (size_t)k * HDIM;
    if (k == 0)
      k_gemv<false><<<256, b256, 0, stream>>>(meta, k, hin, Wk, g);
    else
      k_gemv<true><<<256, b256, 0, stream>>>(meta, k, hin, Wk, g);
    k_init_self<<<128, b256, 0, stream>>>(meta, k + 1, list[k + 1], slot[k], deg, bk, g, hout);
    k_scatter<<<256, b256, 0, stream>>>(ei, E, meta, 4 + k, elist[k], ea, deg,
                                        slot[k], slot[k + 1], g, hout);
    float* tmp = hin; hin = hout; hout = tmp;
  }
  // hin row 0 = target node's h3 (slot 0 of level 3 by construction)

  // head MLP, parallel per-stage kernels (proven in rounds 1-2)
  k_head<256, 512, true ><<<8, b256, 0, stream>>>(hin, Wo1, bo1, v1);
  k_head<512, 512, false><<<8, b256, 0, stream>>>(v1, Wo2, bo2, v2);
  k_head<512, 256, true ><<<4, b256, 0, stream>>>(v2, Wh1, bh1, v1);
  k_head<256, 128, true ><<<2, b256, 0, stream>>>(v1, Wh2, bh2, v2);
  k_final<<<1, 128, 0, stream>>>(v2, Wh3, bh3, meta, out);
}

// Round 7
// 79.711 us; speedup vs baseline: 19.4135x; 1.2923x over previous
//
#include <hip/hip_runtime.h>

#define HDIM 256
#define CAPN 4096
#define CAPE (CAPN * 8)

// meta: [0]=shared slot counter, [5+k]=edge count layer k (k=0..2), [8]=int32 flag.
// map[u]: 0=absent, 1=claim-in-progress, else ((slot+1)<<2)|birth, birth in {0..3}.
// Node u is in S_l  <=>  map[u]>=4 && (map[u]&3) >= l.   (sets are nested)

// Zero map/deg + init meta + detect int64-vs-int32 + seed target, all in one kernel.
// Only block 0 touches meta, so detect/seed don't race the zeroing.
__global__ void k_zero_seed(int* __restrict__ map, float* __restrict__ deg,
                            int* __restrict__ meta, int* __restrict__ nodeof,
                            const int* __restrict__ ei, int E,
                            const int* __restrict__ tgt, int N) {
  int t = tgt[0];
  int tid = blockIdx.x * blockDim.x + threadIdx.x;
  int total = gridDim.x * blockDim.x;
  for (int i = tid; i < N; i += total) map[i] = (i == t) ? 7 : 0;  // target: slot0,birth3
  for (int i = tid; i < CAPN; i += total) deg[i] = 0.0f;
  if (blockIdx.x == 0 && threadIdx.x < 64) {
    bool nz = (threadIdx.x < E) && (ei[2 * threadIdx.x + 1] != 0);
    unsigned long long b = __ballot(nz);
    if (threadIdx.x == 0) {
      meta[8] = (b != 0ULL) ? 1 : 0;  // any nonzero high word => int32
      meta[0] = 1;
      meta[5] = 0; meta[6] = 0; meta[7] = 0;
      nodeof[0] = t;
    }
  }
}

// Expansion step l: edges with col in S_l -> record edge (layer l-1), claim row (birth l-1).
__global__ void k_expand(const int* __restrict__ ei, int E, int* __restrict__ meta,
                         int* __restrict__ map, int* __restrict__ nodeof,
                         int* __restrict__ elist, int ecntIdx, int l) {
  int tid = blockIdx.x * blockDim.x + threadIdx.x;
  int total = gridDim.x * blockDim.x;
  int st = meta[8] ? 1 : 2;
  for (int e = tid; e < E; e += total) {
    int c = ei[(size_t)(E + e) * st];
    int mv = map[c];
    if (mv >= 4 && (mv & 3) >= l) {     // c in S_l (mid-kernel claims have birth l-1: excluded)
      int r = ei[(size_t)e * st];
      int s = atomicAdd(&meta[ecntIdx], 1);
      if (s < CAPE) elist[s] = e;
      if (atomicCAS(&map[r], 0, 1) == 0) {
        int ns = atomicAdd(&meta[0], 1);
        if (ns < CAPN) {
          nodeof[ns] = r;
          map[r] = ((ns + 1) << 2) | (l - 1);
        }
      }
    }
  }
}

// Block-role split: blocks [0,DEGB) accumulate compact in-degree over all E edges;
// blocks [DEGB,..) compute h0[slot] = relu(x[u] @ Wi + bi) for all discovered nodes.
#define DEGB 128
__global__ void __launch_bounds__(256) k_deg_h0(
    const int* __restrict__ ei, const float* __restrict__ ea, int E,
    const int* __restrict__ meta, const int* __restrict__ map,
    const int* __restrict__ nodeof, const float* __restrict__ x,
    const float* __restrict__ Wi, const float* __restrict__ bi,
    float* __restrict__ h, float* __restrict__ deg) {
  int st = meta[8] ? 1 : 2;
  if (blockIdx.x < DEGB) {
    int tid = blockIdx.x * blockDim.x + threadIdx.x;
    int total = DEGB * blockDim.x;
    for (int e = tid; e < E; e += total) {
      int c = ei[(size_t)(E + e) * st];
      int mv = map[c];
      if (mv >= 4) atomicAdd(&deg[(mv >> 2) - 1], ea[e]);
    }
  } else {
    __shared__ float xs[112];
    int ntot = meta[0]; if (ntot > CAPN) ntot = CAPN;
    int j = threadIdx.x;
    for (int s = blockIdx.x - DEGB; s < ntot; s += gridDim.x - DEGB) {
      int u = nodeof[s];
      if (j < 100) xs[j] = x[(size_t)u * 100 + j];
      __syncthreads();
      float acc = bi[j];
#pragma unroll 4
      for (int k = 0; k < 100; ++k) acc = fmaf(xs[k], Wi[k * HDIM + j], acc);
      h[(size_t)s * HDIM + j] = fmaxf(acc, 0.0f);
      __syncthreads();
    }
  }
}

// g[s] = (relu?)(hin[s]) @ W over ALL slots; epilogue initializes hout for S_{k+1} rows:
// hout[s] = bk + dinv^2 * g[s]   (bias + self-loop message), dinv = 1/sqrt(deg+1).
template <bool RELU_IN>
__global__ void __launch_bounds__(256) k_gemv_self(
    const int* __restrict__ meta, int k, const int* __restrict__ map,
    const int* __restrict__ nodeof, const float* __restrict__ hin,
    const float* __restrict__ W, const float* __restrict__ bk,
    const float* __restrict__ deg, float* __restrict__ g, float* __restrict__ hout) {
  __shared__ float hs[HDIM];
  int ntot = meta[0]; if (ntot > CAPN) ntot = CAPN;
  int j = threadIdx.x;
  for (int s = blockIdx.x; s < ntot; s += gridDim.x) {
    float hv = hin[(size_t)s * HDIM + j];
    hs[j] = RELU_IN ? fmaxf(hv, 0.0f) : hv;
    __syncthreads();
    float acc = 0.0f;
#pragma unroll 8
    for (int m = 0; m < HDIM; ++m) acc = fmaf(hs[m], W[m * HDIM + j], acc);
    g[(size_t)s * HDIM + j] = acc;
    int mv = map[nodeof[s]];
    if ((mv & 3) >= k + 1) {  // s in S_{k+1}
      float dv = 1.0f / sqrtf(deg[s] + 1.0f);
      hout[(size_t)s * HDIM + j] = bk[j] + dv * dv * acc;
    }
    __syncthreads();
  }
}

// hout[slot(col)] += dinv(row)*ea*dinv(col) * g[slot(row)] over layer-k active edges.
__global__ void __launch_bounds__(256) k_scatter(
    const int* __restrict__ ei, int E, const int* __restrict__ meta, int ecntIdx,
    const int* __restrict__ elist, const float* __restrict__ ea,
    const int* __restrict__ map, const float* __restrict__ deg,
    const float* __restrict__ g, float* __restrict__ hout) {
  int ne = meta[ecntIdx]; if (ne > CAPE) ne = CAPE;
  int st = meta[8] ? 1 : 2;
  int j = threadIdx.x;
  for (int i = blockIdx.x; i < ne; i += gridDim.x) {
    int e = elist[i];
    int u = ei[(size_t)e * st];
    int v = ei[(size_t)(E + e) * st];
    int mu = map[u], mv = map[v];
    if (mu < 4 || mv < 4) continue;     // capacity-overflow guard (flagged in tail)
    int su = (mu >> 2) - 1, sv = (mv >> 2) - 1;
    float du = 1.0f / sqrtf(deg[su] + 1.0f);
    float dvv = 1.0f / sqrtf(deg[sv] + 1.0f);
    float nrm = du * ea[e] * dvv;
    atomicAdd(&hout[(size_t)sv * HDIM + j], nrm * g[(size_t)su * HDIM + j]);
  }
}

// Head MLP stage (proven): vout[j] = act(vin @ W + b); 64 outputs x 4 K-chunks per block.
template <int KIN, int KOUT, bool RELU>
__global__ void __launch_bounds__(256) k_head(const float* __restrict__ vin,
                                              const float* __restrict__ W,
                                              const float* __restrict__ b,
                                              float* __restrict__ vout) {
  __shared__ float vs[KIN];
  __shared__ float red[4][64];
  int tx = threadIdx.x & 63, ty = threadIdx.x >> 6;
  for (int k = threadIdx.x; k < KIN; k += 256) vs[k] = vin[k];
  __syncthreads();
  int j = blockIdx.x * 64 + tx;
  const int KQ = KIN / 4;
  float acc = 0.0f;
#pragma unroll 4
  for (int k = ty * KQ; k < (ty + 1) * KQ; ++k) acc = fmaf(vs[k], W[(size_t)k * KOUT + j], acc);
  red[ty][tx] = acc;
  __syncthreads();
  if (ty == 0) {
    float r = red[0][tx] + red[1][tx] + red[2][tx] + red[3][tx] + b[j];
    vout[j] = RELU ? fmaxf(r, 0.0f) : r;
  }
}

// Tail: v4 = relu(v3 @ Wh2 + bh2) [256->128], out = v4 @ Wh3 + bh3 [128->5]. One block.
// Side-channel: capacity overflow -> out[4] = code*1e6.
__global__ void __launch_bounds__(256) k_tail(
    const float* __restrict__ vin, const float* __restrict__ Wh2,
    const float* __restrict__ bh2, const float* __restrict__ Wh3,
    const float* __restrict__ bh3, const int* __restrict__ meta,
    float* __restrict__ out) {
  __shared__ float vs[256];
  __shared__ float part[256];
  __shared__ float v4[128];
  int tid = threadIdx.x;
  vs[tid] = vin[tid];
  __syncthreads();
  int o = tid & 127, half = tid >> 7;
  float acc = 0.0f;
#pragma unroll 4
  for (int k = half * 128; k < (half + 1) * 128; ++k)
    acc = fmaf(vs[k], Wh2[(size_t)k * 128 + o], acc);
  part[tid] = acc;
  __syncthreads();
  if (tid < 128) v4[tid] = fmaxf(part[tid] + part[tid + 128] + bh2[tid], 0.0f);
  __syncthreads();
  if (tid < 5) {
    float a = bh3[tid];
#pragma unroll 4
    for (int k = 0; k < 128; ++k) a = fmaf(v4[k], Wh3[k * 5 + tid], a);
    if (tid == 4) {
      int B = 0;
      if (meta[0] > CAPN) B |= 1;
      if (meta[5] > CAPE || meta[6] > CAPE || meta[7] > CAPE) B |= 2;
      if (B) a = 1.0e6f * (float)B;
    }
    out[tid] = a;
  }
}

// Diagnostic: out = [0,0,0,0,D]
__global__ void k_diag(float* __restrict__ out, float D) {
  int tid = threadIdx.x;
  if (tid < 4) out[tid] = 0.0f;
  if (tid == 4) out[tid] = D;
}

extern "C" void kernel_launch(void* const* d_in, const int* in_sizes, int n_in,
                              void* d_out, int out_size, void* d_ws, size_t ws_size,
                              hipStream_t stream) {
  float* out = (float*)d_out;

  // ---- input-mapping tripwire (proven good) ----
  static const long long EXP[18] = {5000000, 600000, 300000, 1, 25600, 256, 196608, 768,
                                    131072, 512, 262144, 512, 131072, 256, 32768, 128, 640, 5};
  if (n_in != 18) {
    k_diag<<<1, 64, 0, stream>>>(out, 3.0e6f + 1000.0f * (float)n_in);
    return;
  }
  for (int i = 0; i < 18; ++i) {
    long long s = in_sizes[i];
    bool ok = (s == EXP[i]) || (i == 1 && s == 2 * EXP[1]);
    if (!ok) {
      k_diag<<<1, 64, 0, stream>>>(out, (float)(i + 1) * 1.0e5f);
      return;
    }
  }

  const float* x   = (const float*)d_in[0];
  const int*   ei  = (const int*)d_in[1];
  const float* ea  = (const float*)d_in[2];
  const int*   tgt = (const int*)d_in[3];
  const float* Wi  = (const float*)d_in[4];
  const float* bi  = (const float*)d_in[5];
  const float* Wg  = (const float*)d_in[6];
  const float* bg  = (const float*)d_in[7];
  const float* Wo1 = (const float*)d_in[8];
  const float* bo1 = (const float*)d_in[9];
  const float* Wo2 = (const float*)d_in[10];
  const float* bo2 = (const float*)d_in[11];
  const float* Wh1 = (const float*)d_in[12];
  const float* bh1 = (const float*)d_in[13];
  const float* Wh2 = (const float*)d_in[14];
  const float* bh2 = (const float*)d_in[15];
  const float* Wh3 = (const float*)d_in[16];
  const float* bh3 = (const float*)d_in[17];

  const int N = 50000, E = 300000;

  // ---- workspace ----
  auto al = [](size_t b) { return (b + 255) & ~(size_t)255; };
  char* ws = (char*)d_ws;
  size_t off = 0;
  auto alloc = [&](size_t bytes) { char* p = ws + off; off += al(bytes); return p; };

  int*   map    = (int*)alloc((size_t)N * 4);
  int*   meta   = (int*)alloc(256);
  float* deg    = (float*)alloc((size_t)CAPN * 4);
  int*   nodeof = (int*)alloc((size_t)CAPN * 4);
  int* elist[3];
  for (int k = 0; k < 3; ++k) elist[k] = (int*)alloc((size_t)CAPE * 4);
  float* g  = (float*)alloc((size_t)CAPN * HDIM * 4);
  float* hA = (float*)alloc((size_t)CAPN * HDIM * 4);
  float* hB = (float*)alloc((size_t)CAPN * HDIM * 4);
  float* headv = (float*)alloc(4096);
  float* v1 = headv;
  float* v2 = headv + 512;

  if (off > ws_size) {
    k_diag<<<1, 64, 0, stream>>>(out, 9.0e6f + (float)(ws_size >> 20));
    return;
  }

  dim3 b256(256);
  int gE = (E + 255) / 256;

  // init + detect + seed in one kernel (replaces the 42us runtime fillBuffer)
  k_zero_seed<<<64, b256, 0, stream>>>(map, deg, meta, nodeof, ei, E, tgt, N);

  // frontier: S3 -> S2 -> S1 -> S0, collecting per-layer edge lists
  for (int l = 3; l >= 1; --l)
    k_expand<<<gE, b256, 0, stream>>>(ei, E, meta, map, nodeof, elist[l - 1], 5 + (l - 1), l);

  // compact in-degree + input projection (independent, block-role split)
  k_deg_h0<<<256, b256, 0, stream>>>(ei, ea, E, meta, map, nodeof, x, Wi, bi, hA, deg);

  // 3 GCN layers on the active subgraph
  float* hin = hA;
  float* hout = hB;
  for (int k = 0; k < 3; ++k) {
    const float* Wk = Wg + (size_t)k * HDIM * HDIM;
    const float* bk = bg + (size_t)k * HDIM;
    if (k == 0)
      k_gemv_self<false><<<256, b256, 0, stream>>>(meta, k, map, nodeof, hin, Wk, bk, deg, g, hout);
    else
      k_gemv_self<true ><<<256, b256, 0, stream>>>(meta, k, map, nodeof, hin, Wk, bk, deg, g, hout);
    k_scatter<<<256, b256, 0, stream>>>(ei, E, meta, 5 + k, elist[k], ea, map, deg, g, hout);
    float* tmp = hin; hin = hout; hout = tmp;
  }
  // hin row 0 = target's h3 (slot 0 seeded at birth)

  // head MLP
  k_head<256, 512, true ><<<8, b256, 0, stream>>>(hin, Wo1, bo1, v1);
  k_head<512, 512, false><<<8, b256, 0, stream>>>(v1, Wo2, bo2, v2);
  k_head<512, 256, true ><<<4, b256, 0, stream>>>(v2, Wh1, bh1, v1);
  k_tail<<<1, b256, 0, stream>>>(v1, Wh2, bh2, Wh3, bh3, meta, out);
}